// Round 1
// baseline (4553.445 us; speedup 1.0000x reference)
//
#include <hip/hip_runtime.h>
#include <math.h>

// ---------------------------------------------------------------------------
// Heterogeneous GraphSAGE (3 types, 6 relations, D=128, L=3) + MLP head.
// fp32 end-to-end (round 0: correctness + baseline counters).
//
// Node row layout (cur / d_out): [performance 0..200000) [artist ..230000) [song ..280000)
// ---------------------------------------------------------------------------

#define NPF 200000
#define NAR 30000
#define NSO 50000

// ---------- gather x0 = emb[nid] ----------
__global__ void k_gather(const int* __restrict__ nid, const float4* __restrict__ emb,
                         float4* __restrict__ dst, int nrow) {
  int i = blockIdx.x * blockDim.x + threadIdx.x;
  if (i >= nrow * 32) return;
  int r = i >> 5, c = i & 31;
  dst[(size_t)r * 32 + c] = emb[(size_t)nid[r] * 32 + c];
}

// ---------- CSR build (per relation, once per launch, reused for 3 layers) ----------
__global__ void k_count(const int* __restrict__ dstv, int E, int* __restrict__ cnt) {
  int i = blockIdx.x * blockDim.x + threadIdx.x;
  if (i < E) atomicAdd(&cnt[dstv[i]], 1);
}

__global__ void k_scan_block(const int* __restrict__ cnt, int n, int* __restrict__ part) {
  __shared__ int sd[256];
  int t = threadIdx.x;
  int base = blockIdx.x * 1024 + t * 4;
  int s = 0;
#pragma unroll
  for (int i = 0; i < 4; ++i) { int idx = base + i; if (idx < n) s += cnt[idx]; }
  sd[t] = s; __syncthreads();
  for (int off = 128; off > 0; off >>= 1) { if (t < off) sd[t] += sd[t + off]; __syncthreads(); }
  if (t == 0) part[blockIdx.x] = sd[0];
}

__global__ void k_scan_top(int* part, int nb) {
  __shared__ int sd[256];
  int t = threadIdx.x;
  int v = (t < nb) ? part[t] : 0;
  sd[t] = v; __syncthreads();
  for (int off = 1; off < 256; off <<= 1) {
    int add = (t >= off) ? sd[t - off] : 0;
    __syncthreads();
    sd[t] += add;
    __syncthreads();
  }
  if (t < nb) part[t] = sd[t] - v;  // exclusive
}

__global__ void k_scan_final(const int* __restrict__ cnt, int n, const int* __restrict__ part,
                             int* __restrict__ rp, int E) {
  __shared__ int sd[256];
  int t = threadIdx.x;
  int base = blockIdx.x * 1024 + t * 4;
  int v[4]; int s = 0;
#pragma unroll
  for (int i = 0; i < 4; ++i) { int idx = base + i; v[i] = (idx < n) ? cnt[idx] : 0; s += v[i]; }
  sd[t] = s; __syncthreads();
  for (int off = 1; off < 256; off <<= 1) {
    int add = (t >= off) ? sd[t - off] : 0;
    __syncthreads();
    sd[t] += add;
    __syncthreads();
  }
  int run = part[blockIdx.x] + sd[t] - s;  // exclusive prefix for this thread's chunk
#pragma unroll
  for (int i = 0; i < 4; ++i) { int idx = base + i; if (idx < n) rp[idx] = run; run += v[i]; }
  if (blockIdx.x == 0 && t == 0) rp[n] = E;
}

__global__ void k_fill(const int* __restrict__ srcv, const int* __restrict__ dstv, int E,
                       const int* __restrict__ rp, int* __restrict__ cur, int* __restrict__ col) {
  int i = blockIdx.x * blockDim.x + threadIdx.x;
  if (i < E) {
    int d = dstv[i];
    int p = atomicAdd(&cur[d], 1);
    col[rp[d] + p] = srcv[i];
  }
}

// ---------- segment mean: msg[d] = mean over neighbors of x_src ----------
// one wave per dst node; thread t owns columns 2t,2t+1 (float2).
__global__ void k_agg(const int* __restrict__ rp, const int* __restrict__ col,
                      const float2* __restrict__ xsrc, float2* __restrict__ msg, int n_dst) {
  int d = blockIdx.x;
  int t = threadIdx.x;  // 64
  int b = rp[d], e = rp[d + 1];
  float ax = 0.f, ay = 0.f;
  for (int j = b; j < e; ++j) {
    int s = col[j];
    float2 v = xsrc[(size_t)s * 64 + t];
    ax += v.x; ay += v.y;
  }
  float inv = (e > b) ? 1.0f / (float)(e - b) : 0.0f;
  msg[(size_t)d * 64 + t] = make_float2(ax * inv, ay * inv);
}

// ---------- SAGE: out = l2norm(msg@Wl + bl + x@Wr); store or accumulate ----------
// 256 threads, 64 rows/block. thread: cg=tid&15 -> cols cg*8..+7, rg4=tid>>4 -> rows rg4*4..+3.
// No LDS: each msg/x element is read by exactly one 16-lane broadcast group once (L1-served);
// W panels (64KB) are L1/L2-resident across blocks.
__global__ __launch_bounds__(256) void k_sage(
    const float* __restrict__ msg, const float* __restrict__ xdst,
    const float* __restrict__ Wl, const float* __restrict__ Wr,
    const float* __restrict__ blv, float* __restrict__ outp,
    int n_dst, int first, int relu_out) {
  int tid = threadIdx.x;
  int row0 = blockIdx.x * 64;
  int cg = tid & 15, rg4 = tid >> 4;
  int c0 = cg * 8;
  int r0 = row0 + rg4 * 4;
  int rr[4];
#pragma unroll
  for (int i = 0; i < 4; ++i) rr[i] = min(r0 + i, n_dst - 1);

  float acc[4][8];
  float4 b0 = *(const float4*)(blv + c0);
  float4 b1 = *(const float4*)(blv + c0 + 4);
#pragma unroll
  for (int i = 0; i < 4; ++i) {
    acc[i][0] = b0.x; acc[i][1] = b0.y; acc[i][2] = b0.z; acc[i][3] = b0.w;
    acc[i][4] = b1.x; acc[i][5] = b1.y; acc[i][6] = b1.z; acc[i][7] = b1.w;
  }

#pragma unroll 4
  for (int k = 0; k < 128; ++k) {
    float4 wl0 = *(const float4*)(Wl + k * 128 + c0);
    float4 wl1 = *(const float4*)(Wl + k * 128 + c0 + 4);
    float4 wr0 = *(const float4*)(Wr + k * 128 + c0);
    float4 wr1 = *(const float4*)(Wr + k * 128 + c0 + 4);
#pragma unroll
    for (int i = 0; i < 4; ++i) {
      float a = msg[(size_t)rr[i] * 128 + k];
      float x = xdst[(size_t)rr[i] * 128 + k];
      acc[i][0] += a * wl0.x + x * wr0.x;
      acc[i][1] += a * wl0.y + x * wr0.y;
      acc[i][2] += a * wl0.z + x * wr0.z;
      acc[i][3] += a * wl0.w + x * wr0.w;
      acc[i][4] += a * wl1.x + x * wr1.x;
      acc[i][5] += a * wl1.y + x * wr1.y;
      acc[i][6] += a * wl1.z + x * wr1.z;
      acc[i][7] += a * wl1.w + x * wr1.w;
    }
  }

#pragma unroll
  for (int i = 0; i < 4; ++i) {
    float s = 0.f;
#pragma unroll
    for (int j = 0; j < 8; ++j) s += acc[i][j] * acc[i][j];
    s += __shfl_xor(s, 1); s += __shfl_xor(s, 2);
    s += __shfl_xor(s, 4); s += __shfl_xor(s, 8);
    float sc = 1.0f / fmaxf(sqrtf(s), 1e-12f);
    int rg = r0 + i;
    if (rg < n_dst) {
      float* p = outp + (size_t)rg * 128 + c0;
      float o[8];
#pragma unroll
      for (int j = 0; j < 8; ++j) o[j] = acc[i][j] * sc;
      if (first) {
        *(float4*)p       = make_float4(o[0], o[1], o[2], o[3]);
        *(float4*)(p + 4) = make_float4(o[4], o[5], o[6], o[7]);
      } else {
        float4 t0 = *(const float4*)p;
        float4 t1 = *(const float4*)(p + 4);
        o[0] += t0.x; o[1] += t0.y; o[2] += t0.z; o[3] += t0.w;
        o[4] += t1.x; o[5] += t1.y; o[6] += t1.z; o[7] += t1.w;
        if (relu_out) {
#pragma unroll
          for (int j = 0; j < 8; ++j) o[j] = fmaxf(o[j], 0.f);
        }
        *(float4*)p       = make_float4(o[0], o[1], o[2], o[3]);
        *(float4*)(p + 4) = make_float4(o[4], o[5], o[6], o[7]);
      }
    }
  }
}

// ---------- head: LN -> relu(h@pw1+pb1) -> @pw2+pb2 -> l2norm, in-place ----------
__global__ __launch_bounds__(256) void k_head(
    float* __restrict__ io, int n,
    const float* __restrict__ lng, const float* __restrict__ lnb,
    const float* __restrict__ w1, const float* __restrict__ pb1v,
    const float* __restrict__ w2, const float* __restrict__ pb2v) {
  __shared__ float Hs[64 * 132];
  int tid = threadIdx.x;
  int row0 = blockIdx.x * 64;

  // phase 0: LayerNorm each row -> Hs   (4 threads per row, 32 cols each)
  {
    int r = tid >> 2, q = tid & 3;
    int rg = row0 + r;
    float v[32];
    if (rg < n) {
#pragma unroll
      for (int j = 0; j < 8; ++j) {
        float4 t4 = *(const float4*)(io + (size_t)rg * 128 + q * 32 + j * 4);
        v[4 * j] = t4.x; v[4 * j + 1] = t4.y; v[4 * j + 2] = t4.z; v[4 * j + 3] = t4.w;
      }
    } else {
#pragma unroll
      for (int j = 0; j < 32; ++j) v[j] = 0.f;
    }
    float s = 0.f, ss = 0.f;
#pragma unroll
    for (int j = 0; j < 32; ++j) { s += v[j]; ss += v[j] * v[j]; }
    s  += __shfl_xor(s, 1);  s  += __shfl_xor(s, 2);
    ss += __shfl_xor(ss, 1); ss += __shfl_xor(ss, 2);
    float mu = s * 0.0078125f;
    float var = ss * 0.0078125f - mu * mu;
    float rs = rsqrtf(var + 1e-5f);
#pragma unroll
    for (int j = 0; j < 32; ++j) {
      int c = q * 32 + j;
      Hs[r * 132 + c] = (v[j] - mu) * rs * lng[c] + lnb[c];
    }
  }
  __syncthreads();

  int cg = tid & 15, rg4 = tid >> 4;
  int c0 = cg * 8;
  int r0 = rg4 * 4;
  float acc[4][8];

  // GEMM1: h @ pw1 + pb1, relu
  {
    float4 b0 = *(const float4*)(pb1v + c0);
    float4 b1 = *(const float4*)(pb1v + c0 + 4);
#pragma unroll
    for (int i = 0; i < 4; ++i) {
      acc[i][0] = b0.x; acc[i][1] = b0.y; acc[i][2] = b0.z; acc[i][3] = b0.w;
      acc[i][4] = b1.x; acc[i][5] = b1.y; acc[i][6] = b1.z; acc[i][7] = b1.w;
    }
  }
#pragma unroll 4
  for (int k = 0; k < 128; ++k) {
    float4 w0 = *(const float4*)(w1 + k * 128 + c0);
    float4 w1v = *(const float4*)(w1 + k * 128 + c0 + 4);
#pragma unroll
    for (int i = 0; i < 4; ++i) {
      float h = Hs[(r0 + i) * 132 + k];
      acc[i][0] += h * w0.x;  acc[i][1] += h * w0.y;
      acc[i][2] += h * w0.z;  acc[i][3] += h * w0.w;
      acc[i][4] += h * w1v.x; acc[i][5] += h * w1v.y;
      acc[i][6] += h * w1v.z; acc[i][7] += h * w1v.w;
    }
  }
  __syncthreads();  // all Hs reads done; reuse the buffer for h1
#pragma unroll
  for (int i = 0; i < 4; ++i) {
    float4 o0 = make_float4(fmaxf(acc[i][0], 0.f), fmaxf(acc[i][1], 0.f),
                            fmaxf(acc[i][2], 0.f), fmaxf(acc[i][3], 0.f));
    float4 o1 = make_float4(fmaxf(acc[i][4], 0.f), fmaxf(acc[i][5], 0.f),
                            fmaxf(acc[i][6], 0.f), fmaxf(acc[i][7], 0.f));
    *(float4*)&Hs[(r0 + i) * 132 + c0]     = o0;
    *(float4*)&Hs[(r0 + i) * 132 + c0 + 4] = o1;
  }
  __syncthreads();

  // GEMM2: h1 @ pw2 + pb2
  {
    float4 b0 = *(const float4*)(pb2v + c0);
    float4 b1 = *(const float4*)(pb2v + c0 + 4);
#pragma unroll
    for (int i = 0; i < 4; ++i) {
      acc[i][0] = b0.x; acc[i][1] = b0.y; acc[i][2] = b0.z; acc[i][3] = b0.w;
      acc[i][4] = b1.x; acc[i][5] = b1.y; acc[i][6] = b1.z; acc[i][7] = b1.w;
    }
  }
#pragma unroll 4
  for (int k = 0; k < 128; ++k) {
    float4 w0 = *(const float4*)(w2 + k * 128 + c0);
    float4 w1v = *(const float4*)(w2 + k * 128 + c0 + 4);
#pragma unroll
    for (int i = 0; i < 4; ++i) {
      float h = Hs[(r0 + i) * 132 + k];
      acc[i][0] += h * w0.x;  acc[i][1] += h * w0.y;
      acc[i][2] += h * w0.z;  acc[i][3] += h * w0.w;
      acc[i][4] += h * w1v.x; acc[i][5] += h * w1v.y;
      acc[i][6] += h * w1v.z; acc[i][7] += h * w1v.w;
    }
  }

  // l2norm + store
#pragma unroll
  for (int i = 0; i < 4; ++i) {
    float s = 0.f;
#pragma unroll
    for (int j = 0; j < 8; ++j) s += acc[i][j] * acc[i][j];
    s += __shfl_xor(s, 1); s += __shfl_xor(s, 2);
    s += __shfl_xor(s, 4); s += __shfl_xor(s, 8);
    float sc = 1.0f / fmaxf(sqrtf(s), 1e-12f);
    int rg = row0 + r0 + i;
    if (rg < n) {
      float* p = io + (size_t)rg * 128 + c0;
      *(float4*)p       = make_float4(acc[i][0] * sc, acc[i][1] * sc, acc[i][2] * sc, acc[i][3] * sc);
      *(float4*)(p + 4) = make_float4(acc[i][4] * sc, acc[i][5] * sc, acc[i][6] * sc, acc[i][7] * sc);
    }
  }
}

// ---------------------------------------------------------------------------
extern "C" void kernel_launch(void* const* d_in, const int* in_sizes, int n_in,
                              void* d_out, int out_size, void* d_ws, size_t ws_size,
                              hipStream_t stream) {
  const int* nid[3] = {(const int*)d_in[0], (const int*)d_in[1], (const int*)d_in[2]};
  const int* eg[6];
  for (int r = 0; r < 6; ++r) eg[r] = (const int*)d_in[3 + r];
  const float* emb[3] = {(const float*)d_in[9], (const float*)d_in[10], (const float*)d_in[11]};
  const float* Wl  = (const float*)d_in[12];
  const float* bl  = (const float*)d_in[13];
  const float* Wr  = (const float*)d_in[14];
  const float* lng = (const float*)d_in[15];
  const float* lnb = (const float*)d_in[16];
  const float* pw1 = (const float*)d_in[17];
  const float* pb1 = (const float*)d_in[18];
  const float* pw2 = (const float*)d_in[19];
  const float* pb2 = (const float*)d_in[20];

  static const int TOFF[3] = {0, NPF, NPF + NAR};          // perf, artist, song row offsets
  static const int TN[3]   = {NPF, NAR, NSO};
  struct RelI { int st, dt, E, first; };
  static const RelI R[6] = {
    {1, 0, 400000, 1},   // artist -> performance
    {0, 2, 400000, 1},   // performance -> song
    {1, 2, 150000, 0},   // artist -> song
    {0, 1, 400000, 1},   // performance -> artist
    {2, 0, 400000, 0},   // song -> performance
    {2, 1, 150000, 0},   // song -> artist
  };
  int col_off[6], rp_off[6];
  { int c = 0, p = 0;
    for (int r = 0; r < 6; ++r) { col_off[r] = c; rp_off[r] = p; c += R[r].E; p += TN[R[r].dt] + 1; } }

  // workspace layout (~256.4 MB)
  float* cur = (float*)d_ws;                         // 280000*128 f32
  float* msg = cur + (size_t)280000 * 128;           // 200000*128 f32
  int* col   = (int*)(msg + (size_t)200000 * 128);   // 1,900,000
  int* rp    = col + 1900000;                        // 560,006
  int* tmp   = rp + 560006;                          // 200,000
  int* part  = tmp + 200000;                         // 1024
  float* dout = (float*)d_out;

  // x0 = emb[nid]
  for (int t = 0; t < 3; ++t) {
    int tot = TN[t] * 32;
    k_gather<<<dim3((tot + 255) / 256), dim3(256), 0, stream>>>(
        nid[t], (const float4*)emb[t], (float4*)(cur + (size_t)TOFF[t] * 128), TN[t]);
  }

  // CSR per relation
  for (int r = 0; r < 6; ++r) {
    int nd = TN[R[r].dt], E = R[r].E;
    hipMemsetAsync(tmp, 0, (size_t)nd * 4, stream);
    k_count<<<dim3((E + 255) / 256), dim3(256), 0, stream>>>(eg[r] + E, E, tmp);
    int nb = (nd + 1023) / 1024;
    k_scan_block<<<dim3(nb), dim3(256), 0, stream>>>(tmp, nd, part);
    k_scan_top<<<dim3(1), dim3(256), 0, stream>>>(part, nb);
    k_scan_final<<<dim3(nb), dim3(256), 0, stream>>>(tmp, nd, part, rp + rp_off[r], E);
    hipMemsetAsync(tmp, 0, (size_t)nd * 4, stream);
    k_fill<<<dim3((E + 255) / 256), dim3(256), 0, stream>>>(
        eg[r], eg[r] + E, E, rp + rp_off[r], tmp, col + col_off[r]);
  }

  // GNN layers; ping-pong cur <-> d_out (layer0: cur->dout, 1: dout->cur, 2: cur->dout)
  for (int layer = 0; layer < 3; ++layer) {
    float* xin  = (layer == 1) ? dout : cur;
    float* xout = (layer == 1) ? cur  : dout;
    int relu_o = (layer < 2) ? 1 : 0;   // applied by the second (+=) relation per dst type
    for (int r = 0; r < 6; ++r) {
      int nd = TN[R[r].dt];
      k_agg<<<dim3(nd), dim3(64), 0, stream>>>(
          rp + rp_off[r], col + col_off[r],
          (const float2*)(xin + (size_t)TOFF[R[r].st] * 128), (float2*)msg, nd);
      const float* wl = Wl + ((size_t)layer * 6 + r) * 16384;
      const float* wr = Wr + ((size_t)layer * 6 + r) * 16384;
      const float* bb = bl + ((size_t)layer * 6 + r) * 128;
      k_sage<<<dim3((nd + 63) / 64), dim3(256), 0, stream>>>(
          msg, xin + (size_t)TOFF[R[r].dt] * 128, wl, wr, bb,
          xout + (size_t)TOFF[R[r].dt] * 128, nd, R[r].first, relu_o);
    }
  }

  // head, in-place on dout
  for (int t = 0; t < 3; ++t) {
    k_head<<<dim3((TN[t] + 63) / 64), dim3(256), 0, stream>>>(
        dout + (size_t)TOFF[t] * 128, TN[t],
        lng + t * 128, lnb + t * 128,
        pw1 + (size_t)t * 16384, pb1 + t * 128,
        pw2 + (size_t)t * 16384, pb2 + t * 128);
  }

  (void)in_sizes; (void)n_in; (void)out_size; (void)ws_size;
}

// Round 5
// 3227.645 us; speedup vs baseline: 1.4108x; 1.4108x over previous
//
#include <hip/hip_runtime.h>
#include <math.h>

// ---------------------------------------------------------------------------
// Heterogeneous GraphSAGE (3 types, 6 relations, D=128, L=3) + MLP head.
// Round 4 (bisect): round-0 code (passed) with ONLY k_sage replaced by the
// 6-term split-bf16 MFMA version. k_agg and k_head are byte-identical to
// round 0. If this fails ~1e-2 the bug is in k_sage_mfma; if it passes the
// bug was in k_head_mfma / 4-wave k_agg.
//
// Node row layout: [performance 0..200000) [artist ..230000) [song ..280000)
// ---------------------------------------------------------------------------

#define NPF 200000
#define NAR 30000
#define NSO 50000

typedef __attribute__((ext_vector_type(8))) short bf16x8;
typedef __attribute__((ext_vector_type(4))) float f32x4;

__device__ __forceinline__ unsigned short f2bf(float f) {
  union { float f; unsigned u; } v; v.f = f;
  unsigned u = v.u;
  u += 0x7FFFu + ((u >> 16) & 1u);
  return (unsigned short)(u >> 16);
}
__device__ __forceinline__ float bf2f(unsigned short h) {
  union { unsigned u; float f; } v; v.u = ((unsigned)h) << 16;
  return v.f;
}

struct BF3 { short h, m, l; };
__device__ __forceinline__ BF3 split3(float f) {
  BF3 r;
  unsigned short hh = f2bf(f);
  float r1 = f - bf2f(hh);
  unsigned short mm = f2bf(r1);
  float r2 = r1 - bf2f(mm);
  r.h = (short)hh; r.m = (short)mm; r.l = (short)f2bf(r2);
  return r;
}

// ---------- gather x0 = emb[nid] ----------
__global__ void k_gather(const int* __restrict__ nid, const float4* __restrict__ emb,
                         float4* __restrict__ dst, int nrow) {
  int i = blockIdx.x * blockDim.x + threadIdx.x;
  if (i >= nrow * 32) return;
  int r = i >> 5, c = i & 31;
  dst[(size_t)r * 32 + c] = emb[(size_t)nid[r] * 32 + c];
}

// ---------- CSR build ----------
__global__ void k_count(const int* __restrict__ dstv, int E, int* __restrict__ cnt) {
  int i = blockIdx.x * blockDim.x + threadIdx.x;
  if (i < E) atomicAdd(&cnt[dstv[i]], 1);
}

__global__ void k_scan_block(const int* __restrict__ cnt, int n, int* __restrict__ part) {
  __shared__ int sd[256];
  int t = threadIdx.x;
  int base = blockIdx.x * 1024 + t * 4;
  int s = 0;
#pragma unroll
  for (int i = 0; i < 4; ++i) { int idx = base + i; if (idx < n) s += cnt[idx]; }
  sd[t] = s; __syncthreads();
  for (int off = 128; off > 0; off >>= 1) { if (t < off) sd[t] += sd[t + off]; __syncthreads(); }
  if (t == 0) part[blockIdx.x] = sd[0];
}

__global__ void k_scan_top(int* part, int nb) {
  __shared__ int sd[256];
  int t = threadIdx.x;
  int v = (t < nb) ? part[t] : 0;
  sd[t] = v; __syncthreads();
  for (int off = 1; off < 256; off <<= 1) {
    int add = (t >= off) ? sd[t - off] : 0;
    __syncthreads();
    sd[t] += add;
    __syncthreads();
  }
  if (t < nb) part[t] = sd[t] - v;  // exclusive
}

__global__ void k_scan_final(const int* __restrict__ cnt, int n, const int* __restrict__ part,
                             int* __restrict__ rp, int E) {
  __shared__ int sd[256];
  int t = threadIdx.x;
  int base = blockIdx.x * 1024 + t * 4;
  int v[4]; int s = 0;
#pragma unroll
  for (int i = 0; i < 4; ++i) { int idx = base + i; v[i] = (idx < n) ? cnt[idx] : 0; s += v[i]; }
  sd[t] = s; __syncthreads();
  for (int off = 1; off < 256; off <<= 1) {
    int add = (t >= off) ? sd[t - off] : 0;
    __syncthreads();
    sd[t] += add;
    __syncthreads();
  }
  int run = part[blockIdx.x] + sd[t] - s;
#pragma unroll
  for (int i = 0; i < 4; ++i) { int idx = base + i; if (idx < n) rp[idx] = run; run += v[i]; }
  if (blockIdx.x == 0 && t == 0) rp[n] = E;
}

__global__ void k_fill(const int* __restrict__ srcv, const int* __restrict__ dstv, int E,
                       const int* __restrict__ rp, int* __restrict__ cur, int* __restrict__ col) {
  int i = blockIdx.x * blockDim.x + threadIdx.x;
  if (i < E) {
    int d = dstv[i];
    int p = atomicAdd(&cur[d], 1);
    col[rp[d] + p] = srcv[i];
  }
}

// ---------- segment mean: one wave per dst node (round-0 version) ----------
__global__ void k_agg(const int* __restrict__ rp, const int* __restrict__ col,
                      const float2* __restrict__ xsrc, float2* __restrict__ msg, int n_dst) {
  int d = blockIdx.x;
  int t = threadIdx.x;  // 64
  int b = rp[d], e = rp[d + 1];
  float ax = 0.f, ay = 0.f;
  for (int j = b; j < e; ++j) {
    int s = col[j];
    float2 v = xsrc[(size_t)s * 64 + t];
    ax += v.x; ay += v.y;
  }
  float inv = (e > b) ? 1.0f / (float)(e - b) : 0.0f;
  msg[(size_t)d * 64 + t] = make_float2(ax * inv, ay * inv);
}

// ---------- pack Wl/Wr into MFMA B-fragment order, bf16 hi/mid/lo ----------
// matrix m: [0,18)=Wl[layer*6+r], [18,36)=Wr
// per-matrix block (49152 ushorts): hi[16384], mid[16384], lo[16384].
// hi index: ((s*8 + t)*64 + lane)*8 + j  ->  W[s*32 + (lane>>4)*8 + j][t*16 + (lane&15)]
#define PKSTRIDE 49152
__global__ void k_packW(const float* __restrict__ Wl, const float* __restrict__ Wr,
                        unsigned short* __restrict__ pk) {
  int gid = blockIdx.x * blockDim.x + threadIdx.x;
  if (gid >= 36 * 4 * 8 * 64) return;
  int lane = gid & 63;
  int t = (gid >> 6) & 7;
  int s = (gid >> 9) & 3;
  int m = gid >> 11;
  const float* src = (m < 18) ? (Wl + (size_t)m * 16384) : (Wr + (size_t)(m - 18) * 16384);
  int n = t * 16 + (lane & 15);
  int k0 = s * 32 + (lane >> 4) * 8;
  unsigned short* hi = pk + (size_t)m * PKSTRIDE + ((size_t)(s * 8 + t) * 64 + lane) * 8;
  unsigned short* mid = hi + 16384;
  unsigned short* lo = hi + 32768;
#pragma unroll
  for (int j = 0; j < 8; ++j) {
    float f = src[(size_t)(k0 + j) * 128 + n];
    BF3 w = split3(f);
    hi[j] = (unsigned short)w.h;
    mid[j] = (unsigned short)w.m;
    lo[j] = (unsigned short)w.l;
  }
}

// 6-product split-bf16 MFMA accumulate (drops only O(2^-24) terms)
#define MFMA6(ah, am, al, bh, bm, blo, acc)                                     \
  acc = __builtin_amdgcn_mfma_f32_16x16x32_bf16(ah, bh, acc, 0, 0, 0);          \
  acc = __builtin_amdgcn_mfma_f32_16x16x32_bf16(am, bh, acc, 0, 0, 0);          \
  acc = __builtin_amdgcn_mfma_f32_16x16x32_bf16(ah, bm, acc, 0, 0, 0);          \
  acc = __builtin_amdgcn_mfma_f32_16x16x32_bf16(al, bh, acc, 0, 0, 0);          \
  acc = __builtin_amdgcn_mfma_f32_16x16x32_bf16(am, bm, acc, 0, 0, 0);          \
  acc = __builtin_amdgcn_mfma_f32_16x16x32_bf16(ah, blo, acc, 0, 0, 0);

// ---------- SAGE via MFMA: out = l2norm(msg@Wl + bl + x@Wr); store/accumulate ----------
// 256 thr = 4 waves; wave handles 16 rows x 128 cols (8 tiles of 16x16).
__global__ __launch_bounds__(256) void k_sage_mfma(
    const float* __restrict__ msg, const float* __restrict__ xdst,
    const unsigned short* __restrict__ pkl, const unsigned short* __restrict__ pkr,
    const float* __restrict__ blv, float* __restrict__ outp,
    int n_dst, int first, int relu_out) {
  int lane = threadIdx.x & 63;
  int wave = threadIdx.x >> 6;
  int row0 = blockIdx.x * 64 + wave * 16;
  int cg = lane & 15, qg = lane >> 4;
  int ar = min(row0 + cg, n_dst - 1);  // A row (lane&15 indexes M)
  int kb = qg * 8;

  f32x4 acc[8];
#pragma unroll
  for (int t = 0; t < 8; ++t) acc[t] = (f32x4){0.f, 0.f, 0.f, 0.f};

#pragma unroll
  for (int sm = 0; sm < 2; ++sm) {
    const float* A = sm ? xdst : msg;
    const unsigned short* pk = sm ? pkr : pkl;
#pragma unroll
    for (int s = 0; s < 4; ++s) {
      const float* ap = A + (size_t)ar * 128 + s * 32 + kb;
      float4 f0 = *(const float4*)ap;
      float4 f1 = *(const float4*)(ap + 4);
      float fa[8] = {f0.x, f0.y, f0.z, f0.w, f1.x, f1.y, f1.z, f1.w};
      bf16x8 ah, am, al;
#pragma unroll
      for (int j = 0; j < 8; ++j) {
        BF3 w = split3(fa[j]);
        ah[j] = w.h; am[j] = w.m; al[j] = w.l;
      }
      const unsigned short* pb = pk + (size_t)s * 4096 + (size_t)lane * 8;
#pragma unroll
      for (int t = 0; t < 8; ++t) {
        bf16x8 bh  = *(const bf16x8*)(pb + (size_t)t * 512);
        bf16x8 bm  = *(const bf16x8*)(pb + (size_t)t * 512 + 16384);
        bf16x8 blo = *(const bf16x8*)(pb + (size_t)t * 512 + 32768);
        MFMA6(ah, am, al, bh, bm, blo, acc[t]);
      }
    }
  }

  // bias (per output column)
#pragma unroll
  for (int t = 0; t < 8; ++t) {
    float bv = blv[t * 16 + cg];
#pragma unroll
    for (int j = 0; j < 4; ++j) acc[t][j] += bv;
  }
  // l2norm: row r = row0 + qg*4 + j; cols spread over 8 tiles x 16 lanes
  float ss[4];
#pragma unroll
  for (int j = 0; j < 4; ++j) {
    float s = 0.f;
#pragma unroll
    for (int t = 0; t < 8; ++t) s += acc[t][j] * acc[t][j];
    s += __shfl_xor(s, 1); s += __shfl_xor(s, 2);
    s += __shfl_xor(s, 4); s += __shfl_xor(s, 8);
    ss[j] = 1.0f / fmaxf(sqrtf(s), 1e-12f);
  }
#pragma unroll
  for (int j = 0; j < 4; ++j) {
    int r = row0 + qg * 4 + j;
    if (r < n_dst) {
      float* p = outp + (size_t)r * 128 + cg;
      if (first) {
#pragma unroll
        for (int t = 0; t < 8; ++t) p[t * 16] = acc[t][j] * ss[j];
      } else {
#pragma unroll
        for (int t = 0; t < 8; ++t) {
          float v = p[t * 16] + acc[t][j] * ss[j];
          if (relu_out) v = fmaxf(v, 0.f);
          p[t * 16] = v;
        }
      }
    }
  }
}

// ---------- head (round-0 fp32 version): LN -> relu(h@pw1+pb1) -> @pw2+pb2 -> l2norm ----------
__global__ __launch_bounds__(256) void k_head(
    float* __restrict__ io, int n,
    const float* __restrict__ lng, const float* __restrict__ lnb,
    const float* __restrict__ w1, const float* __restrict__ pb1v,
    const float* __restrict__ w2, const float* __restrict__ pb2v) {
  __shared__ float Hs[64 * 132];
  int tid = threadIdx.x;
  int row0 = blockIdx.x * 64;

  // phase 0: LayerNorm each row -> Hs   (4 threads per row, 32 cols each)
  {
    int r = tid >> 2, q = tid & 3;
    int rg = row0 + r;
    float v[32];
    if (rg < n) {
#pragma unroll
      for (int j = 0; j < 8; ++j) {
        float4 t4 = *(const float4*)(io + (size_t)rg * 128 + q * 32 + j * 4);
        v[4 * j] = t4.x; v[4 * j + 1] = t4.y; v[4 * j + 2] = t4.z; v[4 * j + 3] = t4.w;
      }
    } else {
#pragma unroll
      for (int j = 0; j < 32; ++j) v[j] = 0.f;
    }
    float s = 0.f, ss = 0.f;
#pragma unroll
    for (int j = 0; j < 32; ++j) { s += v[j]; ss += v[j] * v[j]; }
    s  += __shfl_xor(s, 1);  s  += __shfl_xor(s, 2);
    ss += __shfl_xor(ss, 1); ss += __shfl_xor(ss, 2);
    float mu = s * 0.0078125f;
    float var = ss * 0.0078125f - mu * mu;
    float rs = rsqrtf(var + 1e-5f);
#pragma unroll
    for (int j = 0; j < 32; ++j) {
      int c = q * 32 + j;
      Hs[r * 132 + c] = (v[j] - mu) * rs * lng[c] + lnb[c];
    }
  }
  __syncthreads();

  int cg = tid & 15, rg4 = tid >> 4;
  int c0 = cg * 8;
  int r0 = rg4 * 4;
  float acc[4][8];

  // GEMM1: h @ pw1 + pb1, relu
  {
    float4 b0 = *(const float4*)(pb1v + c0);
    float4 b1 = *(const float4*)(pb1v + c0 + 4);
#pragma unroll
    for (int i = 0; i < 4; ++i) {
      acc[i][0] = b0.x; acc[i][1] = b0.y; acc[i][2] = b0.z; acc[i][3] = b0.w;
      acc[i][4] = b1.x; acc[i][5] = b1.y; acc[i][6] = b1.z; acc[i][7] = b1.w;
    }
  }
#pragma unroll 4
  for (int k = 0; k < 128; ++k) {
    float4 w0 = *(const float4*)(w1 + k * 128 + c0);
    float4 w1v = *(const float4*)(w1 + k * 128 + c0 + 4);
#pragma unroll
    for (int i = 0; i < 4; ++i) {
      float h = Hs[(r0 + i) * 132 + k];
      acc[i][0] += h * w0.x;  acc[i][1] += h * w0.y;
      acc[i][2] += h * w0.z;  acc[i][3] += h * w0.w;
      acc[i][4] += h * w1v.x; acc[i][5] += h * w1v.y;
      acc[i][6] += h * w1v.z; acc[i][7] += h * w1v.w;
    }
  }
  __syncthreads();  // all Hs reads done; reuse the buffer for h1
#pragma unroll
  for (int i = 0; i < 4; ++i) {
    float4 o0 = make_float4(fmaxf(acc[i][0], 0.f), fmaxf(acc[i][1], 0.f),
                            fmaxf(acc[i][2], 0.f), fmaxf(acc[i][3], 0.f));
    float4 o1 = make_float4(fmaxf(acc[i][4], 0.f), fmaxf(acc[i][5], 0.f),
                            fmaxf(acc[i][6], 0.f), fmaxf(acc[i][7], 0.f));
    *(float4*)&Hs[(r0 + i) * 132 + c0]     = o0;
    *(float4*)&Hs[(r0 + i) * 132 + c0 + 4] = o1;
  }
  __syncthreads();

  // GEMM2: h1 @ pw2 + pb2
  {
    float4 b0 = *(const float4*)(pb2v + c0);
    float4 b1 = *(const float4*)(pb2v + c0 + 4);
#pragma unroll
    for (int i = 0; i < 4; ++i) {
      acc[i][0] = b0.x; acc[i][1] = b0.y; acc[i][2] = b0.z; acc[i][3] = b0.w;
      acc[i][4] = b1.x; acc[i][5] = b1.y; acc[i][6] = b1.z; acc[i][7] = b1.w;
    }
  }
#pragma unroll 4
  for (int k = 0; k < 128; ++k) {
    float4 w0 = *(const float4*)(w2 + k * 128 + c0);
    float4 w1v = *(const float4*)(w2 + k * 128 + c0 + 4);
#pragma unroll
    for (int i = 0; i < 4; ++i) {
      float h = Hs[(r0 + i) * 132 + k];
      acc[i][0] += h * w0.x;  acc[i][1] += h * w0.y;
      acc[i][2] += h * w0.z;  acc[i][3] += h * w0.w;
      acc[i][4] += h * w1v.x; acc[i][5] += h * w1v.y;
      acc[i][6] += h * w1v.z; acc[i][7] += h * w1v.w;
    }
  }

  // l2norm + store
#pragma unroll
  for (int i = 0; i < 4; ++i) {
    float s = 0.f;
#pragma unroll
    for (int j = 0; j < 8; ++j) s += acc[i][j] * acc[i][j];
    s += __shfl_xor(s, 1); s += __shfl_xor(s, 2);
    s += __shfl_xor(s, 4); s += __shfl_xor(s, 8);
    float sc = 1.0f / fmaxf(sqrtf(s), 1e-12f);
    int rg = row0 + r0 + i;
    if (rg < n) {
      float* p = io + (size_t)rg * 128 + c0;
      *(float4*)p       = make_float4(acc[i][0] * sc, acc[i][1] * sc, acc[i][2] * sc, acc[i][3] * sc);
      *(float4*)(p + 4) = make_float4(acc[i][4] * sc, acc[i][5] * sc, acc[i][6] * sc, acc[i][7] * sc);
    }
  }
}

// ---------------------------------------------------------------------------
extern "C" void kernel_launch(void* const* d_in, const int* in_sizes, int n_in,
                              void* d_out, int out_size, void* d_ws, size_t ws_size,
                              hipStream_t stream) {
  const int* nid[3] = {(const int*)d_in[0], (const int*)d_in[1], (const int*)d_in[2]};
  const int* eg[6];
  for (int r = 0; r < 6; ++r) eg[r] = (const int*)d_in[3 + r];
  const float* emb[3] = {(const float*)d_in[9], (const float*)d_in[10], (const float*)d_in[11]};
  const float* Wl  = (const float*)d_in[12];
  const float* bl  = (const float*)d_in[13];
  const float* Wr  = (const float*)d_in[14];
  const float* lng = (const float*)d_in[15];
  const float* lnb = (const float*)d_in[16];
  const float* pw1 = (const float*)d_in[17];
  const float* pb1 = (const float*)d_in[18];
  const float* pw2 = (const float*)d_in[19];
  const float* pb2 = (const float*)d_in[20];

  static const int TOFF[3] = {0, NPF, NPF + NAR};
  static const int TN[3]   = {NPF, NAR, NSO};
  struct RelI { int st, dt, E, first; };
  static const RelI R[6] = {
    {1, 0, 400000, 1},   // artist -> performance
    {0, 2, 400000, 1},   // performance -> song
    {1, 2, 150000, 0},   // artist -> song
    {0, 1, 400000, 1},   // performance -> artist
    {2, 0, 400000, 0},   // song -> performance
    {2, 1, 150000, 0},   // song -> artist
  };
  int col_off[6], rp_off[6];
  { int c = 0, p = 0;
    for (int r = 0; r < 6; ++r) { col_off[r] = c; rp_off[r] = p; c += R[r].E; p += TN[R[r].dt] + 1; } }

  // workspace layout (~259.9 MB)
  float* cur = (float*)d_ws;                         // 280000*128 f32
  float* msg = cur + (size_t)280000 * 128;           // 200000*128 f32
  int* col   = (int*)(msg + (size_t)200000 * 128);   // 1,900,000
  int* rp    = col + 1900000;                        // 560,006
  int* tmp   = rp + 560006;                          // 200,000
  int* part  = tmp + 200000;                         // 1024
  size_t pk_off = ((size_t)((char*)(part + 1024) - (char*)d_ws) + 255) & ~(size_t)255;
  unsigned short* pkw = (unsigned short*)((char*)d_ws + pk_off);  // 36*49152 ushorts = 3.5 MB
  float* dout = (float*)d_out;

  // pack Wl/Wr (36 matrices) into MFMA fragment order, bf16 hi/mid/lo
  k_packW<<<dim3(288), dim3(256), 0, stream>>>(Wl, Wr, pkw);

  // x0 = emb[nid]
  for (int t = 0; t < 3; ++t) {
    int tot = TN[t] * 32;
    k_gather<<<dim3((tot + 255) / 256), dim3(256), 0, stream>>>(
        nid[t], (const float4*)emb[t], (float4*)(cur + (size_t)TOFF[t] * 128), TN[t]);
  }

  // CSR per relation
  for (int r = 0; r < 6; ++r) {
    int nd = TN[R[r].dt], E = R[r].E;
    hipMemsetAsync(tmp, 0, (size_t)nd * 4, stream);
    k_count<<<dim3((E + 255) / 256), dim3(256), 0, stream>>>(eg[r] + E, E, tmp);
    int nb = (nd + 1023) / 1024;
    k_scan_block<<<dim3(nb), dim3(256), 0, stream>>>(tmp, nd, part);
    k_scan_top<<<dim3(1), dim3(256), 0, stream>>>(part, nb);
    k_scan_final<<<dim3(nb), dim3(256), 0, stream>>>(tmp, nd, part, rp + rp_off[r], E);
    hipMemsetAsync(tmp, 0, (size_t)nd * 4, stream);
    k_fill<<<dim3((E + 255) / 256), dim3(256), 0, stream>>>(
        eg[r], eg[r] + E, E, rp + rp_off[r], tmp, col + col_off[r]);
  }

  // GNN layers; ping-pong cur <-> d_out (layer0: cur->dout, 1: dout->cur, 2: cur->dout)
  for (int layer = 0; layer < 3; ++layer) {
    float* xin  = (layer == 1) ? dout : cur;
    float* xout = (layer == 1) ? cur  : dout;
    int relu_o = (layer < 2) ? 1 : 0;
    for (int r = 0; r < 6; ++r) {
      int nd = TN[R[r].dt];
      k_agg<<<dim3(nd), dim3(64), 0, stream>>>(
          rp + rp_off[r], col + col_off[r],
          (const float2*)(xin + (size_t)TOFF[R[r].st] * 128), (float2*)msg, nd);
      int m = layer * 6 + r;
      const unsigned short* pkl = pkw + (size_t)m * PKSTRIDE;
      const unsigned short* pkr = pkw + (size_t)(18 + m) * PKSTRIDE;
      const float* bb = bl + ((size_t)layer * 6 + r) * 128;
      k_sage_mfma<<<dim3((nd + 63) / 64), dim3(256), 0, stream>>>(
          msg, xin + (size_t)TOFF[R[r].dt] * 128, pkl, pkr, bb,
          xout + (size_t)TOFF[R[r].dt] * 128, nd, R[r].first, relu_o);
    }
  }

  // head, in-place on dout (round-0 fp32 version)
  for (int t = 0; t < 3; ++t) {
    k_head<<<dim3((TN[t] + 63) / 64), dim3(256), 0, stream>>>(
        dout + (size_t)TOFF[t] * 128, TN[t],
        lng + t * 128, lnb + t * 128,
        pw1 + (size_t)t * 16384, pb1 + t * 128,
        pw2 + (size_t)t * 16384, pb2 + t * 128);
  }

  (void)in_sizes; (void)n_in; (void)out_size; (void)ws_size;
}